// Round 9
// baseline (259.612 us; speedup 1.0000x reference)
//
#include <hip/hip_runtime.h>
#include <hip/hip_bf16.h>
#include <hip/hip_fp16.h>

#define NEG_SLOPE 0.2f
#define EPB  8192   // edges per coarse-sort block
#define MAXC 2048   // max coarse bins (= ceil(n_dst/32)); 50000/32 = 1563

typedef __attribute__((ext_vector_type(8))) short bf16x8;
typedef __attribute__((ext_vector_type(4))) float f32x4;

__device__ __forceinline__ float b2f_lo(unsigned u) { return __uint_as_float(u << 16); }
__device__ __forceinline__ float b2f_hi(unsigned u) { return __uint_as_float(u & 0xffff0000u); }

__device__ __forceinline__ short f2b(float x) {
    unsigned u = __float_as_uint(x);
    unsigned r = (u + 0x7fffu + ((u >> 16) & 1u)) >> 16;
    return (short)r;
}

// ---------------------------------------------------------------------------
// 0) Pack W into MFMA B-fragment order (bf16) + fused logit matrix V = W·A'
//    (9th n-tile) and c = b·A'.
// ---------------------------------------------------------------------------
__global__ __launch_bounds__(256) void pack_kernel(
    const float* __restrict__ W_src, const float* __restrict__ W_dst,
    const float* __restrict__ b_src, const float* __restrict__ b_dst,
    const float* __restrict__ attn,  // [8,32]
    uint4* __restrict__ wp_src, uint4* __restrict__ wp_dst,
    float* __restrict__ c_all)       // [16]
{
    const int e = blockIdx.x * 256 + threadIdx.x;
    if (e < 4608) {
        const int which = e / 2304;
        const int e2 = e % 2304;
        const float* W = which ? W_dst : W_src;
        uint4* wp = which ? wp_dst : wp_src;
        const int aoff = which ? 16 : 0;
        short out[8];
        if (e2 < 2048) {                    // W tiles
            const int t = e2 >> 8, q = (e2 >> 6) & 3, l = e2 & 63;
            const int kbase = (l >> 4) * 8 + q * 32;
            const int n = t * 16 + (l & 15);
            #pragma unroll
            for (int j = 0; j < 8; ++j) out[j] = f2b(W[(size_t)(kbase + j) * 128 + n]);
            *(uint4*)&wp[(t * 4 + q) * 64 + l] = *(uint4*)out;
        } else {                            // V tile (fused logits)
            const int e3 = e2 - 2048;
            const int q = e3 >> 6, l = e3 & 63;
            const int kbase = (l >> 4) * 8 + q * 32;
            const int n = l & 15;
            #pragma unroll
            for (int j = 0; j < 8; ++j) {
                float v = 0.f;
                if (n < 8) {
                    for (int dd = 0; dd < 16; ++dd)
                        v += W[(size_t)(kbase + j) * 128 + n * 16 + dd] * attn[n * 32 + aoff + dd];
                }
                out[j] = f2b(v);
            }
            *(uint4*)&wp[(32 + q) * 64 + l] = *(uint4*)out;
        }
    } else if (e < 4624) {                  // c = b·A'
        const int k = e - 4608;
        const int which = k >> 3, kk = k & 7;
        const float* bb = which ? b_dst : b_src;
        const int aoff = which ? 16 : 0;
        float v = 0.f;
        for (int dd = 0; dd < 16; ++dd) v += bb[kk * 16 + dd] * attn[kk * 32 + aoff + dd];
        c_all[k] = v;
    }
}

// ---------------------------------------------------------------------------
// coarse histogram body (LDS, no global atomics): H[bin][block] matrix
// ---------------------------------------------------------------------------
__device__ __forceinline__ void hist_body(
    const int* __restrict__ dst_idx, int* __restrict__ Hmat,
    int nEdges, int nCoarse, int nCB, int bx)
{
    __shared__ int h[MAXC];
    const int t = threadIdx.x;
    for (int i = t; i < nCoarse; i += 256) h[i] = 0;
    __syncthreads();
    const int e0 = bx * EPB;
    const int e1 = min(e0 + EPB, nEdges);
    for (int e = e0 + t; e < e1; e += 256) atomicAdd(&h[dst_idx[e] >> 5], 1);
    __syncthreads();
    for (int i = t; i < nCoarse; i += 256) Hmat[(size_t)i * nCB + bx] = h[i];
}

// ---------------------------------------------------------------------------
// MFMA projection body: h = feat·W + b (bf16 in, fp32 acc), fused logit via
// 9th n-tile. Wave = 2 m-tiles (32 rows); block = 128 rows.
// ---------------------------------------------------------------------------
template<bool STORE_H>
__device__ __forceinline__ void proj_body(
    const float* __restrict__ feat, const uint4* __restrict__ wp,
    const float* __restrict__ b, const float* __restrict__ cvec,
    short* __restrict__ hs_out, float* __restrict__ el_out,
    int N, int bx)
{
    const int t = threadIdx.x;
    const int lane = t & 63;
    const int w = t >> 6;
    const int m  = lane & 15;
    const int q8 = lane >> 4;
    const int row0 = bx * 128 + w * 32;

    f32x4 acc0[9], acc1[9];
    #pragma unroll
    for (int tt = 0; tt < 8; ++tt) {
        const float bn = b[tt * 16 + m];
        acc0[tt] = (f32x4){bn, bn, bn, bn};
        acc1[tt] = (f32x4){bn, bn, bn, bn};
    }
    acc0[8] = (f32x4){0.f, 0.f, 0.f, 0.f};
    acc1[8] = (f32x4){0.f, 0.f, 0.f, 0.f};

    int rowA0 = row0 + m;      if (rowA0 >= N) rowA0 = N - 1;
    int rowA1 = row0 + 16 + m; if (rowA1 >= N) rowA1 = N - 1;
    const float* f0 = feat + (size_t)rowA0 * 128 + q8 * 8;
    const float* f1 = feat + (size_t)rowA1 * 128 + q8 * 8;
    const bf16x8* wpv = (const bf16x8*)wp;

    #pragma unroll
    for (int kc = 0; kc < 4; ++kc) {
        const float4 fa0 = *(const float4*)(f0 + kc * 32);
        const float4 fb0 = *(const float4*)(f0 + kc * 32 + 4);
        const float4 fa1 = *(const float4*)(f1 + kc * 32);
        const float4 fb1 = *(const float4*)(f1 + kc * 32 + 4);
        bf16x8 a0, a1;
        a0[0]=f2b(fa0.x); a0[1]=f2b(fa0.y); a0[2]=f2b(fa0.z); a0[3]=f2b(fa0.w);
        a0[4]=f2b(fb0.x); a0[5]=f2b(fb0.y); a0[6]=f2b(fb0.z); a0[7]=f2b(fb0.w);
        a1[0]=f2b(fa1.x); a1[1]=f2b(fa1.y); a1[2]=f2b(fa1.z); a1[3]=f2b(fa1.w);
        a1[4]=f2b(fb1.x); a1[5]=f2b(fb1.y); a1[6]=f2b(fb1.z); a1[7]=f2b(fb1.w);
        #pragma unroll
        for (int tt = 0; tt < 8; ++tt) {
            const bf16x8 bf = wpv[(tt * 4 + kc) * 64 + lane];
            acc0[tt] = __builtin_amdgcn_mfma_f32_16x16x32_bf16(a0, bf, acc0[tt], 0, 0, 0);
            acc1[tt] = __builtin_amdgcn_mfma_f32_16x16x32_bf16(a1, bf, acc1[tt], 0, 0, 0);
        }
        {
            const bf16x8 bv = wpv[(32 + kc) * 64 + lane];
            acc0[8] = __builtin_amdgcn_mfma_f32_16x16x32_bf16(a0, bv, acc0[8], 0, 0, 0);
            acc1[8] = __builtin_amdgcn_mfma_f32_16x16x32_bf16(a1, bv, acc1[8], 0, 0, 0);
        }
    }

    #pragma unroll
    for (int half = 0; half < 2; ++half) {
        const f32x4* acc = half ? acc1 : acc0;
        const int rbase = row0 + half * 16 + q8 * 4;
        #pragma unroll
        for (int reg = 0; reg < 4; ++reg) {
            const int row = rbase + reg;
            if (row < N) {
                if (STORE_H) {
                    #pragma unroll
                    for (int tt = 0; tt < 8; ++tt)
                        hs_out[(size_t)row * 128 + tt * 16 + m] = f2b(acc[tt][reg]);
                }
                if (m < 8) el_out[(size_t)row * 8 + m] = acc[8][reg] + cvec[m];
            }
        }
    }
}

// ---------------------------------------------------------------------------
// 1) fused: coarse histogram + both MFMA projections (disjoint pipes).
// ---------------------------------------------------------------------------
__global__ __launch_bounds__(256, 2) void fused_proj_hist_kernel(
    const float* __restrict__ feat_src, const float* __restrict__ feat_dst,
    const uint4* __restrict__ wp_src, const uint4* __restrict__ wp_dst,
    const float* __restrict__ b_src, const float* __restrict__ b_dst,
    const float* __restrict__ c_all,
    short* __restrict__ hs, float* __restrict__ el, float* __restrict__ er,
    const int* __restrict__ dst_idx, int* __restrict__ Hmat,
    int n_src, int n_dst, int nEdges, int nCoarse, int nCB, int pSrcBlocks)
{
    int bx = blockIdx.x;
    if (bx < nCB) { hist_body(dst_idx, Hmat, nEdges, nCoarse, nCB, bx); return; }
    bx -= nCB;
    if (bx < pSrcBlocks) {
        proj_body<true>(feat_src, wp_src, b_src, c_all, hs, el, n_src, bx);
        return;
    }
    bx -= pSrcBlocks;
    proj_body<false>(feat_dst, wp_dst, b_dst, c_all + 8, nullptr, er, n_dst, bx);
}

// ---------------------------------------------------------------------------
// 2a) partial sums per 1024-block over flat array
// ---------------------------------------------------------------------------
__global__ __launch_bounds__(1024) void scan_part_kernel(
    const int* __restrict__ cnt, int* __restrict__ part, int n)
{
    __shared__ int wsum[16];
    const int t = threadIdx.x;
    const int i = blockIdx.x * 1024 + t;
    int v = (i < n) ? cnt[i] : 0;
    #pragma unroll
    for (int s = 32; s > 0; s >>= 1) v += __shfl_down(v, s, 64);
    if ((t & 63) == 0) wsum[t >> 6] = v;
    __syncthreads();
    if (t < 16) {
        int x = wsum[t];
        #pragma unroll
        for (int s = 8; s > 0; s >>= 1) x += __shfl_down(x, s, 64);
        if (t == 0) part[blockIdx.x] = x;
    }
}

// ---------------------------------------------------------------------------
// 2b) single-block exclusive scan of partials; S[n] = total
// ---------------------------------------------------------------------------
__global__ __launch_bounds__(1024) void scan_top_kernel(
    int* __restrict__ part, int* __restrict__ S, int nPart, int n)
{
    __shared__ int buf[1024];
    const int t = threadIdx.x;
    const int v = (t < nPart) ? part[t] : 0;
    buf[t] = v;
    __syncthreads();
    #pragma unroll
    for (int s = 1; s < 1024; s <<= 1) {
        const int add = (t >= s) ? buf[t - s] : 0;
        __syncthreads();
        buf[t] += add;
        __syncthreads();
    }
    if (t < nPart) part[t] = buf[t] - v;        // exclusive
    if (t == 1023) S[n] = buf[1023];            // total
}

// ---------------------------------------------------------------------------
// 2c) per-block local exclusive scan + base -> S
// ---------------------------------------------------------------------------
__global__ __launch_bounds__(1024) void scan_local_kernel(
    const int* __restrict__ cnt, const int* __restrict__ part,
    int* __restrict__ S, int n)
{
    __shared__ int buf[1024];
    const int t = threadIdx.x;
    const int i = blockIdx.x * 1024 + t;
    const int v = (i < n) ? cnt[i] : 0;
    buf[t] = v;
    __syncthreads();
    #pragma unroll
    for (int s = 1; s < 1024; s <<= 1) {
        const int add = (t >= s) ? buf[t - s] : 0;
        __syncthreads();
        buf[t] += add;
        __syncthreads();
    }
    if (i < n) S[i] = part[blockIdx.x] + buf[t] - v;
}

// ---------------------------------------------------------------------------
// 3) coarse scatter: LDS-rank scatter of packed (src<<5 | dst&31).
// ---------------------------------------------------------------------------
__global__ __launch_bounds__(256) void coarse_scatter_kernel(
    const int* __restrict__ src_idx, const int* __restrict__ dst_idx,
    const int* __restrict__ S, int* __restrict__ coarse,
    int nEdges, int nCoarse, int nCB)
{
    __shared__ int base_s[MAXC];
    __shared__ int cur_s[MAXC];
    const int t = threadIdx.x, bx = blockIdx.x;
    for (int i = t; i < nCoarse; i += 256) {
        base_s[i] = S[(size_t)i * nCB + bx];
        cur_s[i]  = 0;
    }
    __syncthreads();
    const int e0 = bx * EPB;
    const int e1 = min(e0 + EPB, nEdges);
    for (int e = e0 + t; e < e1; e += 256) {
        const int d = dst_idx[e];
        const int s = src_idx[e];
        const int bin = d >> 5;
        const int lr = atomicAdd(&cur_s[bin], 1);
        coarse[base_s[bin] + lr] = (s << 5) | (d & 31);
    }
}

// ---------------------------------------------------------------------------
// 4) fine sort + WEIGHTS: one block per coarse bin (32 dsts). LDS counting
//    sort; per edge also computes all 8 heads' unnormalized attention
//    weights ee = exp(leakyrelu(el[s]+er[d])) ONCE (vs 64 redundant lane
//    copies in the old reduce) and stores them as fp16 pw[pos][8].
// ---------------------------------------------------------------------------
__global__ __launch_bounds__(256) void fine_sort_kernel(
    const int* __restrict__ coarse, const int* __restrict__ S,
    const float* __restrict__ el,   // [N_src,8]
    const float* __restrict__ er,   // [N_dst,8]
    int* __restrict__ off, int* __restrict__ sorted_src,
    unsigned short* __restrict__ pw, // [nEdges][8] fp16
    int nEdges, int n_dst, int nCoarse, int nCB)
{
    __shared__ int h[32];
    __shared__ int cu[32];
    __shared__ float erL[32 * 8];
    const int t = threadIdx.x, c = blockIdx.x;
    const int base = S[(size_t)c * nCB];
    const int endp = (c + 1 < nCoarse) ? S[(size_t)(c + 1) * nCB] : nEdges;
    if (t < 32) h[t] = 0;
    {   // preload er rows for this bin's 32 dsts: erL[d*8+k], t = d*8+k
        const int d = c * 32 + (t >> 3);
        erL[t] = (d < n_dst) ? er[(size_t)d * 8 + (t & 7)] : 0.f;
    }
    __syncthreads();
    for (int i = base + t; i < endp; i += 256) atomicAdd(&h[coarse[i] & 31], 1);
    __syncthreads();
    if (t == 0) {
        int run = 0;
        #pragma unroll
        for (int j = 0; j < 32; ++j) {
            cu[j] = run;
            const int d = c * 32 + j;
            if (d < n_dst) off[d] = base + run;
            run += h[j];
        }
    }
    __syncthreads();
    for (int i = base + t; i < endp; i += 256) {
        const int v = coarse[i];
        const int d = v & 31;
        const int s = v >> 5;
        const int p = atomicAdd(&cu[d], 1);
        sorted_src[base + p] = s;
        const float4 e0 = *(const float4*)(el + (size_t)s * 8);
        const float4 e1 = *(const float4*)(el + (size_t)s * 8 + 4);
        const float xs[8] = {e0.x, e0.y, e0.z, e0.w, e1.x, e1.y, e1.z, e1.w};
        unsigned short w[8];
        #pragma unroll
        for (int k = 0; k < 8; ++k) {
            float x = xs[k] + erL[d * 8 + k];
            x = (x >= 0.f) ? x : NEG_SLOPE * x;
            const __half hw = __float2half(__expf(x));
            w[k] = __half_as_ushort(hw);
        }
        *(uint4*)(pw + (size_t)(base + p) * 8) = *(uint4*)w;
    }
    if (c == 0 && t == 0) off[n_dst] = nEdges;
}

// ---------------------------------------------------------------------------
// 5) reduce: one wave per dst, HALF-WAVE per edge (lane owns 4 channels).
//    Weights precomputed (fp16) -> no el gather, no exp, no leaky in the
//    hot loop: per edge just w-load + cvt + 4 expand + 4 fma + es add.
// ---------------------------------------------------------------------------
__global__ __launch_bounds__(256) void reduce_kernel(
    const int* __restrict__ sorted_src, const int* __restrict__ off,
    const unsigned short* __restrict__ hs, // [N_src,128] bf16 bits
    const unsigned short* __restrict__ pw, // [nEdges][8] fp16
    float* __restrict__ out,               // [N_dst,128]
    int n_dst)
{
    const int wid = blockIdx.x * 4 + (threadIdx.x >> 6);
    if (wid >= n_dst) return;
    const int lane = threadIdx.x & 63;
    const int sub  = lane >> 5;       // which edge of the pair
    const int l32  = lane & 31;       // channel group: 4*l32 .. 4*l32+3
    const int k    = l32 >> 2;        // head
    const int k2   = k & 6;           // even head index for paired 4B w-load
    const int khi  = k & 1;
    const int beg = off[wid], end = off[wid + 1];

    float a0 = 0.f, a1 = 0.f, a2 = 0.f, a3 = 0.f, es = 0.f;
    int i = beg + sub;
    for (; i + 2 < end; i += 4) {     // edges i and i+2 for this half
        const int sA = sorted_src[i];
        const int sB = sorted_src[i + 2];
        const unsigned wpA = *(const unsigned*)(pw + (size_t)i * 8 + k2);
        const unsigned wpB = *(const unsigned*)(pw + (size_t)(i + 2) * 8 + k2);
        const uint2 uA = ((const uint2*)(hs + (size_t)sA * 128))[l32];
        const uint2 uB = ((const uint2*)(hs + (size_t)sB * 128))[l32];
        const unsigned short usA = khi ? (unsigned short)(wpA >> 16) : (unsigned short)(wpA & 0xffff);
        const unsigned short usB = khi ? (unsigned short)(wpB >> 16) : (unsigned short)(wpB & 0xffff);
        const float eA = __half2float(__ushort_as_half(usA));
        const float eB = __half2float(__ushort_as_half(usB));
        es += eA + eB;
        a0 = fmaf(eA, b2f_lo(uA.x), a0); a1 = fmaf(eA, b2f_hi(uA.x), a1);
        a2 = fmaf(eA, b2f_lo(uA.y), a2); a3 = fmaf(eA, b2f_hi(uA.y), a3);
        a0 = fmaf(eB, b2f_lo(uB.x), a0); a1 = fmaf(eB, b2f_hi(uB.x), a1);
        a2 = fmaf(eB, b2f_lo(uB.y), a2); a3 = fmaf(eB, b2f_hi(uB.y), a3);
    }
    for (; i < end; i += 2) {
        const int s = sorted_src[i];
        const unsigned wp4 = *(const unsigned*)(pw + (size_t)i * 8 + k2);
        const uint2 u = ((const uint2*)(hs + (size_t)s * 128))[l32];
        const unsigned short us = khi ? (unsigned short)(wp4 >> 16) : (unsigned short)(wp4 & 0xffff);
        const float ee = __half2float(__ushort_as_half(us));
        es += ee;
        a0 = fmaf(ee, b2f_lo(u.x), a0); a1 = fmaf(ee, b2f_hi(u.x), a1);
        a2 = fmaf(ee, b2f_lo(u.y), a2); a3 = fmaf(ee, b2f_hi(u.y), a3);
    }
    // combine the two halves (channel sets match lane<->lane+32)
    es += __shfl_xor(es, 32);
    a0 += __shfl_xor(a0, 32);
    a1 += __shfl_xor(a1, 32);
    a2 += __shfl_xor(a2, 32);
    a3 += __shfl_xor(a3, 32);
    if (sub == 0) {
        const float inv = (es > 0.f) ? 1.f / es : 0.f;
        float4 o;
        o.x = a0 * inv; o.y = a1 * inv; o.z = a2 * inv; o.w = a3 * inv;
        *(float4*)(out + (size_t)wid * 128 + l32 * 4) = o;
    }
}

extern "C" void kernel_launch(void* const* d_in, const int* in_sizes, int n_in,
                              void* d_out, int out_size, void* d_ws, size_t ws_size,
                              hipStream_t stream) {
    const float* feat_src = (const float*)d_in[0];
    const float* feat_dst = (const float*)d_in[1];
    const float* W_src    = (const float*)d_in[2];
    const float* b_src    = (const float*)d_in[3];
    const float* W_dst    = (const float*)d_in[4];
    const float* b_dst    = (const float*)d_in[5];
    const float* attn     = (const float*)d_in[6];
    const int*   src_idx  = (const int*)d_in[7];
    const int*   dst_idx  = (const int*)d_in[8];
    float* out = (float*)d_out;

    const int n_src  = in_sizes[0] / 128;
    const int n_dst  = in_sizes[1] / 128;
    const int nEdges = in_sizes[7];

    const int nCoarse = (n_dst + 31) >> 5;                 // 1563
    const int nCB     = (nEdges + EPB - 1) / EPB;          // 196
    const int nH      = nCoarse * nCB;                     // ~306k
    const int nPart   = (nH + 1023) / 1024;                // ~300
    const int pSrc    = (n_src + 127) / 128;
    const int pDst    = (n_dst + 127) / 128;

    // workspace layout
    __hip_bfloat16* hs = (__hip_bfloat16*)d_ws;            // n_src*128 bf16
    float* el   = (float*)(hs + (size_t)n_src * 128);      // n_src*8
    float* er   = el + (size_t)n_src * 8;                  // n_dst*8
    int*   off  = (int*)(er + (size_t)n_dst * 8);          // n_dst+1 (+pad)
    int*   part = off + n_dst + 4;                         // <=1024
    int*   Hmat = part + 1024;                             // nH
    int*   Sarr = Hmat + nH;                               // nH+1 (+pad)
    int*   coarse = Sarr + nH + 4;                         // nEdges (packed)
    int*   sorted_src = coarse + nEdges;                   // nEdges
    unsigned short* pw = (unsigned short*)(sorted_src + nEdges); // nEdges*8 fp16
    uintptr_t p = (uintptr_t)(pw + (size_t)nEdges * 8);
    p = (p + 15) & ~(uintptr_t)15;
    uint4* wp_src = (uint4*)p;                             // 36*64 uint4
    uint4* wp_dst = wp_src + 36 * 64;                      // 36*64 uint4
    float* c_all  = (float*)(wp_dst + 36 * 64);            // 16 floats

    pack_kernel<<<19, 256, 0, stream>>>(W_src, W_dst, b_src, b_dst, attn,
                                        wp_src, wp_dst, c_all);

    fused_proj_hist_kernel<<<nCB + pSrc + pDst, 256, 0, stream>>>(
        feat_src, feat_dst, wp_src, wp_dst, b_src, b_dst, c_all,
        (short*)hs, el, er, dst_idx, Hmat,
        n_src, n_dst, nEdges, nCoarse, nCB, pSrc);

    scan_part_kernel<<<nPart, 1024, 0, stream>>>(Hmat, part, nH);
    scan_top_kernel<<<1, 1024, 0, stream>>>(part, Sarr, nPart, nH);
    scan_local_kernel<<<nPart, 1024, 0, stream>>>(Hmat, part, Sarr, nH);

    coarse_scatter_kernel<<<nCB, 256, 0, stream>>>(src_idx, dst_idx, Sarr,
                                                   coarse, nEdges, nCoarse, nCB);
    fine_sort_kernel<<<nCoarse, 256, 0, stream>>>(coarse, Sarr, el, er,
                                                  off, sorted_src, pw,
                                                  nEdges, n_dst, nCoarse, nCB);

    reduce_kernel<<<(n_dst + 3) / 4, 256, 0, stream>>>(sorted_src, off,
        (const unsigned short*)hs, pw, out, n_dst);
}

// Round 10
// 241.444 us; speedup vs baseline: 1.0752x; 1.0752x over previous
//
#include <hip/hip_runtime.h>
#include <hip/hip_bf16.h>
#include <hip/hip_fp16.h>

#define NEG_SLOPE 0.2f
#define EPB   8192   // edges per scatter block
#define CAP   4096   // arena slots per coarse bin (mean 2048, sigma 45 -> 45-sigma margin)
#define MAXC  1024   // max coarse bins; ceil(50000/64) = 782

typedef __attribute__((ext_vector_type(8))) short bf16x8;
typedef __attribute__((ext_vector_type(4))) float f32x4;

__device__ __forceinline__ float b2f_lo(unsigned u) { return __uint_as_float(u << 16); }
__device__ __forceinline__ float b2f_hi(unsigned u) { return __uint_as_float(u & 0xffff0000u); }

__device__ __forceinline__ short f2b(float x) {
    unsigned u = __float_as_uint(x);
    unsigned r = (u + 0x7fffu + ((u >> 16) & 1u)) >> 16;
    return (short)r;
}

// ---------------------------------------------------------------------------
// 0) Pack W into MFMA B-fragment order (bf16) + fused logit matrix V = W·A'
//    (9th n-tile), c = b·A', and init the per-bin arena cursors.
// ---------------------------------------------------------------------------
__global__ __launch_bounds__(256) void pack_kernel(
    const float* __restrict__ W_src, const float* __restrict__ W_dst,
    const float* __restrict__ b_src, const float* __restrict__ b_dst,
    const float* __restrict__ attn,  // [8,32]
    uint4* __restrict__ wp_src, uint4* __restrict__ wp_dst,
    float* __restrict__ c_all,       // [16]
    int* __restrict__ cursor, int nCoarse)
{
    const int e = blockIdx.x * 256 + threadIdx.x;
    if (e < 4608) {
        const int which = e / 2304;
        const int e2 = e % 2304;
        const float* W = which ? W_dst : W_src;
        uint4* wp = which ? wp_dst : wp_src;
        const int aoff = which ? 16 : 0;
        short out[8];
        if (e2 < 2048) {                    // W tiles
            const int t = e2 >> 8, q = (e2 >> 6) & 3, l = e2 & 63;
            const int kbase = (l >> 4) * 8 + q * 32;
            const int n = t * 16 + (l & 15);
            #pragma unroll
            for (int j = 0; j < 8; ++j) out[j] = f2b(W[(size_t)(kbase + j) * 128 + n]);
            *(uint4*)&wp[(t * 4 + q) * 64 + l] = *(uint4*)out;
        } else {                            // V tile (fused logits)
            const int e3 = e2 - 2048;
            const int q = e3 >> 6, l = e3 & 63;
            const int kbase = (l >> 4) * 8 + q * 32;
            const int n = l & 15;
            #pragma unroll
            for (int j = 0; j < 8; ++j) {
                float v = 0.f;
                if (n < 8) {
                    for (int dd = 0; dd < 16; ++dd)
                        v += W[(size_t)(kbase + j) * 128 + n * 16 + dd] * attn[n * 32 + aoff + dd];
                }
                out[j] = f2b(v);
            }
            *(uint4*)&wp[(32 + q) * 64 + l] = *(uint4*)out;
        }
    } else if (e < 4624) {                  // c = b·A'
        const int k = e - 4608;
        const int which = k >> 3, kk = k & 7;
        const float* bb = which ? b_dst : b_src;
        const int aoff = which ? 16 : 0;
        float v = 0.f;
        for (int dd = 0; dd < 16; ++dd) v += bb[kk * 16 + dd] * attn[kk * 32 + aoff + dd];
        c_all[k] = v;
    } else if (e < 4624 + nCoarse) {        // arena cursor init
        const int c = e - 4624;
        cursor[c] = c * CAP;
    }
}

// ---------------------------------------------------------------------------
// scatter body: LDS per-bin count -> one chunk reservation per bin (returning
// atomic) -> scatter packed (s<<6 | d&63) into the bin's arena. No big scans.
// ---------------------------------------------------------------------------
__device__ __forceinline__ void scatter_body(
    const int* __restrict__ src_idx, const int* __restrict__ dst_idx,
    int* __restrict__ cursor, int* __restrict__ coarse,
    int nEdges, int nCoarse, int bx)
{
    __shared__ int lcnt[MAXC];
    __shared__ int lbase[MAXC];
    const int t = threadIdx.x;
    for (int i = t; i < nCoarse; i += 256) lcnt[i] = 0;
    __syncthreads();
    const int e0 = bx * EPB;
    const int e1 = min(e0 + EPB, nEdges);
    for (int e = e0 + t; e < e1; e += 256) atomicAdd(&lcnt[dst_idx[e] >> 6], 1);
    __syncthreads();
    for (int i = t; i < nCoarse; i += 256) {
        const int c = lcnt[i];
        lbase[i] = c ? atomicAdd(&cursor[i], c) : 0;
        lcnt[i] = 0;                       // reuse as running cursor
    }
    __syncthreads();
    for (int e = e0 + t; e < e1; e += 256) {
        const int d = dst_idx[e];
        const int s = src_idx[e];
        const int bin = d >> 6;
        const int lr = atomicAdd(&lcnt[bin], 1);
        const int pos = lbase[bin] + lr;
        if (pos < (bin + 1) * CAP)         // 45-sigma safety clamp
            coarse[pos] = (s << 6) | (d & 63);
    }
}

// ---------------------------------------------------------------------------
// MFMA projection body: h = feat·W + b (bf16 in, fp32 acc), fused logit via
// 9th n-tile. Wave = 2 m-tiles (32 rows); block = 128 rows.
// ---------------------------------------------------------------------------
template<bool STORE_H>
__device__ __forceinline__ void proj_body(
    const float* __restrict__ feat, const uint4* __restrict__ wp,
    const float* __restrict__ b, const float* __restrict__ cvec,
    short* __restrict__ hs_out, float* __restrict__ el_out,
    int N, int bx)
{
    const int t = threadIdx.x;
    const int lane = t & 63;
    const int w = t >> 6;
    const int m  = lane & 15;
    const int q8 = lane >> 4;
    const int row0 = bx * 128 + w * 32;

    f32x4 acc0[9], acc1[9];
    #pragma unroll
    for (int tt = 0; tt < 8; ++tt) {
        const float bn = b[tt * 16 + m];
        acc0[tt] = (f32x4){bn, bn, bn, bn};
        acc1[tt] = (f32x4){bn, bn, bn, bn};
    }
    acc0[8] = (f32x4){0.f, 0.f, 0.f, 0.f};
    acc1[8] = (f32x4){0.f, 0.f, 0.f, 0.f};

    int rowA0 = row0 + m;      if (rowA0 >= N) rowA0 = N - 1;
    int rowA1 = row0 + 16 + m; if (rowA1 >= N) rowA1 = N - 1;
    const float* f0 = feat + (size_t)rowA0 * 128 + q8 * 8;
    const float* f1 = feat + (size_t)rowA1 * 128 + q8 * 8;
    const bf16x8* wpv = (const bf16x8*)wp;

    #pragma unroll
    for (int kc = 0; kc < 4; ++kc) {
        const float4 fa0 = *(const float4*)(f0 + kc * 32);
        const float4 fb0 = *(const float4*)(f0 + kc * 32 + 4);
        const float4 fa1 = *(const float4*)(f1 + kc * 32);
        const float4 fb1 = *(const float4*)(f1 + kc * 32 + 4);
        bf16x8 a0, a1;
        a0[0]=f2b(fa0.x); a0[1]=f2b(fa0.y); a0[2]=f2b(fa0.z); a0[3]=f2b(fa0.w);
        a0[4]=f2b(fb0.x); a0[5]=f2b(fb0.y); a0[6]=f2b(fb0.z); a0[7]=f2b(fb0.w);
        a1[0]=f2b(fa1.x); a1[1]=f2b(fa1.y); a1[2]=f2b(fa1.z); a1[3]=f2b(fa1.w);
        a1[4]=f2b(fb1.x); a1[5]=f2b(fb1.y); a1[6]=f2b(fb1.z); a1[7]=f2b(fb1.w);
        #pragma unroll
        for (int tt = 0; tt < 8; ++tt) {
            const bf16x8 bf = wpv[(tt * 4 + kc) * 64 + lane];
            acc0[tt] = __builtin_amdgcn_mfma_f32_16x16x32_bf16(a0, bf, acc0[tt], 0, 0, 0);
            acc1[tt] = __builtin_amdgcn_mfma_f32_16x16x32_bf16(a1, bf, acc1[tt], 0, 0, 0);
        }
        {
            const bf16x8 bv = wpv[(32 + kc) * 64 + lane];
            acc0[8] = __builtin_amdgcn_mfma_f32_16x16x32_bf16(a0, bv, acc0[8], 0, 0, 0);
            acc1[8] = __builtin_amdgcn_mfma_f32_16x16x32_bf16(a1, bv, acc1[8], 0, 0, 0);
        }
    }

    #pragma unroll
    for (int half = 0; half < 2; ++half) {
        const f32x4* acc = half ? acc1 : acc0;
        const int rbase = row0 + half * 16 + q8 * 4;
        #pragma unroll
        for (int reg = 0; reg < 4; ++reg) {
            const int row = rbase + reg;
            if (row < N) {
                if (STORE_H) {
                    #pragma unroll
                    for (int tt = 0; tt < 8; ++tt)
                        hs_out[(size_t)row * 128 + tt * 16 + m] = f2b(acc[tt][reg]);
                }
                if (m < 8) el_out[(size_t)row * 8 + m] = acc[8][reg] + cvec[m];
            }
        }
    }
}

// ---------------------------------------------------------------------------
// 1) fused: arena scatter (latency/atomic-bound) + both MFMA projections.
// ---------------------------------------------------------------------------
__global__ __launch_bounds__(256, 2) void fused_kernel(
    const float* __restrict__ feat_src, const float* __restrict__ feat_dst,
    const uint4* __restrict__ wp_src, const uint4* __restrict__ wp_dst,
    const float* __restrict__ b_src, const float* __restrict__ b_dst,
    const float* __restrict__ c_all,
    short* __restrict__ hs, float* __restrict__ el, float* __restrict__ er,
    const int* __restrict__ src_idx, const int* __restrict__ dst_idx,
    int* __restrict__ cursor, int* __restrict__ coarse,
    int n_src, int n_dst, int nEdges, int nCoarse, int nSB, int pSrcBlocks)
{
    int bx = blockIdx.x;
    if (bx < nSB) { scatter_body(src_idx, dst_idx, cursor, coarse, nEdges, nCoarse, bx); return; }
    bx -= nSB;
    if (bx < pSrcBlocks) {
        proj_body<true>(feat_src, wp_src, b_src, c_all, hs, el, n_src, bx);
        return;
    }
    bx -= pSrcBlocks;
    proj_body<false>(feat_dst, wp_dst, b_dst, c_all + 8, nullptr, er, n_dst, bx);
}

// ---------------------------------------------------------------------------
// 2) binscan: one block. counts[c] = cursor[c]-c*CAP; exclusive scan ->
//    outbase[] (contiguous output bases); off[n_dst] = total.
// ---------------------------------------------------------------------------
__global__ __launch_bounds__(1024) void binscan_kernel(
    const int* __restrict__ cursor, int* __restrict__ outbase,
    int* __restrict__ off, int nCoarse, int n_dst)
{
    __shared__ int buf[1024];
    const int t = threadIdx.x;
    int v = 0;
    if (t < nCoarse) {
        v = cursor[t] - t * CAP;
        v = max(0, min(v, CAP));
    }
    buf[t] = v;
    __syncthreads();
    #pragma unroll
    for (int s = 1; s < 1024; s <<= 1) {
        const int add = (t >= s) ? buf[t - s] : 0;
        __syncthreads();
        buf[t] += add;
        __syncthreads();
    }
    if (t < nCoarse) outbase[t] = buf[t] - v;   // exclusive
    if (t == nCoarse - 1) {
        outbase[nCoarse] = buf[t];              // total
        off[n_dst] = buf[t];
    }
}

// ---------------------------------------------------------------------------
// 3) fine sort + weights: one block per 64-dst bin. Sort bin into LDS, then
//    a SEQUENTIAL output pass writes sorted_src (ushort) and pw (fp16 x8)
//    fully coalesced. Weights ee = exp(leakyrelu(el[s]+er[d])) computed once
//    per edge here.
// ---------------------------------------------------------------------------
__global__ __launch_bounds__(256) void fine_sort_kernel(
    const int* __restrict__ coarse, const int* __restrict__ outbase,
    const float* __restrict__ el,   // [N_src,8]
    const float* __restrict__ er,   // [N_dst,8]
    int* __restrict__ off, unsigned short* __restrict__ sorted_src,
    unsigned short* __restrict__ pw, // [nEdges][8] fp16
    int n_dst, int nCoarse)
{
    __shared__ int fpk[CAP];        // 16 KB
    __shared__ int h[64];
    __shared__ int cu[64];
    __shared__ float erL[64 * 8];
    const int t = threadIdx.x, c = blockIdx.x;
    const int base_in = c * CAP;
    const int obase = outbase[c];
    const int cnt = outbase[c + 1] - obase;
    for (int i = t; i < 512; i += 256) {
        const int d = c * 64 + (i >> 3);
        erL[i] = (d < n_dst) ? er[(size_t)d * 8 + (i & 7)] : 0.f;
    }
    if (t < 64) h[t] = 0;
    __syncthreads();
    for (int i = t; i < cnt; i += 256) atomicAdd(&h[coarse[base_in + i] & 63], 1);
    __syncthreads();
    if (t == 0) {
        int run = 0;
        #pragma unroll
        for (int j = 0; j < 64; ++j) {
            cu[j] = run;
            const int d = c * 64 + j;
            if (d < n_dst) off[d] = obase + run;
            run += h[j];
        }
    }
    __syncthreads();
    for (int i = t; i < cnt; i += 256) {
        const int v = coarse[base_in + i];
        const int p = atomicAdd(&cu[v & 63], 1);
        fpk[p] = v;
    }
    __syncthreads();
    for (int i = t; i < cnt; i += 256) {
        const int v = fpk[i];
        const int s = v >> 6;
        const int dl = v & 63;
        const float4 e0 = *(const float4*)(el + (size_t)s * 8);
        const float4 e1 = *(const float4*)(el + (size_t)s * 8 + 4);
        const float xs[8] = {e0.x, e0.y, e0.z, e0.w, e1.x, e1.y, e1.z, e1.w};
        unsigned short w[8];
        #pragma unroll
        for (int k = 0; k < 8; ++k) {
            float x = xs[k] + erL[dl * 8 + k];
            x = (x >= 0.f) ? x : NEG_SLOPE * x;
            w[k] = __half_as_ushort(__float2half(__expf(x)));
        }
        *(uint4*)(pw + (size_t)(obase + i) * 8) = *(uint4*)w;  // coalesced
        sorted_src[obase + i] = (unsigned short)s;             // coalesced
    }
}

// ---------------------------------------------------------------------------
// 4) reduce: one wave per dst, half-wave per edge (lane owns 4 channels).
//    Precomputed fp16 weights; ushort src indices.
// ---------------------------------------------------------------------------
__global__ __launch_bounds__(256) void reduce_kernel(
    const unsigned short* __restrict__ sorted_src, const int* __restrict__ off,
    const unsigned short* __restrict__ hs, // [N_src,128] bf16 bits
    const unsigned short* __restrict__ pw, // [nEdges][8] fp16
    float* __restrict__ out,               // [N_dst,128]
    int n_dst)
{
    const int wid = blockIdx.x * 4 + (threadIdx.x >> 6);
    if (wid >= n_dst) return;
    const int lane = threadIdx.x & 63;
    const int sub  = lane >> 5;       // which edge of the pair
    const int l32  = lane & 31;       // channel group: 4*l32 .. 4*l32+3
    const int k    = l32 >> 2;        // head
    const int k2   = k & 6;           // even head index for 4B w-load
    const int khi  = k & 1;
    const int beg = off[wid], end = off[wid + 1];

    float a0 = 0.f, a1 = 0.f, a2 = 0.f, a3 = 0.f, es = 0.f;
    int i = beg + sub;
    for (; i + 2 < end; i += 4) {
        const int sA = sorted_src[i];
        const int sB = sorted_src[i + 2];
        const unsigned wpA = *(const unsigned*)(pw + (size_t)i * 8 + k2);
        const unsigned wpB = *(const unsigned*)(pw + (size_t)(i + 2) * 8 + k2);
        const uint2 uA = ((const uint2*)(hs + (size_t)sA * 128))[l32];
        const uint2 uB = ((const uint2*)(hs + (size_t)sB * 128))[l32];
        const unsigned short usA = khi ? (unsigned short)(wpA >> 16) : (unsigned short)(wpA & 0xffff);
        const unsigned short usB = khi ? (unsigned short)(wpB >> 16) : (unsigned short)(wpB & 0xffff);
        const float eA = __half2float(__ushort_as_half(usA));
        const float eB = __half2float(__ushort_as_half(usB));
        es += eA + eB;
        a0 = fmaf(eA, b2f_lo(uA.x), a0); a1 = fmaf(eA, b2f_hi(uA.x), a1);
        a2 = fmaf(eA, b2f_lo(uA.y), a2); a3 = fmaf(eA, b2f_hi(uA.y), a3);
        a0 = fmaf(eB, b2f_lo(uB.x), a0); a1 = fmaf(eB, b2f_hi(uB.x), a1);
        a2 = fmaf(eB, b2f_lo(uB.y), a2); a3 = fmaf(eB, b2f_hi(uB.y), a3);
    }
    for (; i < end; i += 2) {
        const int s = sorted_src[i];
        const unsigned wp4 = *(const unsigned*)(pw + (size_t)i * 8 + k2);
        const uint2 u = ((const uint2*)(hs + (size_t)s * 128))[l32];
        const unsigned short us = khi ? (unsigned short)(wp4 >> 16) : (unsigned short)(wp4 & 0xffff);
        const float ee = __half2float(__ushort_as_half(us));
        es += ee;
        a0 = fmaf(ee, b2f_lo(u.x), a0); a1 = fmaf(ee, b2f_hi(u.x), a1);
        a2 = fmaf(ee, b2f_lo(u.y), a2); a3 = fmaf(ee, b2f_hi(u.y), a3);
    }
    es += __shfl_xor(es, 32);
    a0 += __shfl_xor(a0, 32);
    a1 += __shfl_xor(a1, 32);
    a2 += __shfl_xor(a2, 32);
    a3 += __shfl_xor(a3, 32);
    if (sub == 0) {
        const float inv = (es > 0.f) ? 1.f / es : 0.f;
        float4 o;
        o.x = a0 * inv; o.y = a1 * inv; o.z = a2 * inv; o.w = a3 * inv;
        *(float4*)(out + (size_t)wid * 128 + l32 * 4) = o;
    }
}

extern "C" void kernel_launch(void* const* d_in, const int* in_sizes, int n_in,
                              void* d_out, int out_size, void* d_ws, size_t ws_size,
                              hipStream_t stream) {
    const float* feat_src = (const float*)d_in[0];
    const float* feat_dst = (const float*)d_in[1];
    const float* W_src    = (const float*)d_in[2];
    const float* b_src    = (const float*)d_in[3];
    const float* W_dst    = (const float*)d_in[4];
    const float* b_dst    = (const float*)d_in[5];
    const float* attn     = (const float*)d_in[6];
    const int*   src_idx  = (const int*)d_in[7];
    const int*   dst_idx  = (const int*)d_in[8];
    float* out = (float*)d_out;

    const int n_src  = in_sizes[0] / 128;
    const int n_dst  = in_sizes[1] / 128;
    const int nEdges = in_sizes[7];

    const int nCoarse = (n_dst + 63) >> 6;                 // 782
    const int nSB     = (nEdges + EPB - 1) / EPB;          // 196
    const int pSrc    = (n_src + 127) / 128;
    const int pDst    = (n_dst + 127) / 128;

    // workspace layout (16B-aligned chunks)
    unsigned short* hs = (unsigned short*)d_ws;            // n_src*128 bf16 (12.8 MB)
    unsigned short* pw = hs + (size_t)n_src * 128;         // nEdges*8 fp16 (25.6 MB)
    float* el = (float*)(pw + (size_t)nEdges * 8);         // n_src*8
    float* er = el + (size_t)n_src * 8;                    // n_dst*8
    int* off     = (int*)(er + (size_t)n_dst * 8);         // n_dst+1 (+pad)
    int* outbase = off + n_dst + 4;                        // nCoarse+1 (+pad)
    int* cursor  = outbase + nCoarse + 4;                  // nCoarse
    uintptr_t p = (uintptr_t)(cursor + nCoarse);
    p = (p + 15) & ~(uintptr_t)15;
    int* coarse = (int*)p;                                 // nCoarse*CAP (12.8 MB)
    unsigned short* sorted_src = (unsigned short*)(coarse + (size_t)nCoarse * CAP); // nEdges
    uintptr_t p2 = (uintptr_t)(sorted_src + nEdges);
    p2 = (p2 + 15) & ~(uintptr_t)15;
    uint4* wp_src = (uint4*)p2;                            // 36*64 uint4
    uint4* wp_dst = wp_src + 36 * 64;                      // 36*64 uint4
    float* c_all  = (float*)(wp_dst + 36 * 64);            // 16 floats

    pack_kernel<<<22, 256, 0, stream>>>(W_src, W_dst, b_src, b_dst, attn,
                                        wp_src, wp_dst, c_all, cursor, nCoarse);

    fused_kernel<<<nSB + pSrc + pDst, 256, 0, stream>>>(
        feat_src, feat_dst, wp_src, wp_dst, b_src, b_dst, c_all,
        (short*)hs, el, er, src_idx, dst_idx, cursor, coarse,
        n_src, n_dst, nEdges, nCoarse, nSB, pSrc);

    binscan_kernel<<<1, 1024, 0, stream>>>(cursor, outbase, off, nCoarse, n_dst);

    fine_sort_kernel<<<nCoarse, 256, 0, stream>>>(coarse, outbase, el, er,
                                                  off, sorted_src, pw,
                                                  n_dst, nCoarse);

    reduce_kernel<<<(n_dst + 3) / 4, 256, 0, stream>>>(sorted_src, off,
        hs, pw, out, n_dst);
}

// Round 11
// 238.345 us; speedup vs baseline: 1.0892x; 1.0130x over previous
//
#include <hip/hip_runtime.h>
#include <hip/hip_bf16.h>

#define NEG_SLOPE 0.2f
#define EPB   8192   // edges per scatter block
#define CAP   4096   // arena slots per 64-dst coarse bin (mean 2048, sigma 45)
#define MAXC  1024   // max coarse bins; ceil(50000/64) = 782

typedef __attribute__((ext_vector_type(8))) short bf16x8;
typedef __attribute__((ext_vector_type(4))) float f32x4;

__device__ __forceinline__ float b2f_lo(unsigned u) { return __uint_as_float(u << 16); }
__device__ __forceinline__ float b2f_hi(unsigned u) { return __uint_as_float(u & 0xffff0000u); }

__device__ __forceinline__ short f2b(float x) {
    unsigned u = __float_as_uint(x);
    unsigned r = (u + 0x7fffu + ((u >> 16) & 1u)) >> 16;
    return (short)r;
}

// ---------------------------------------------------------------------------
// 0) Pack W into MFMA B-fragment order (bf16) + fused logit matrix V = W·A'
//    (9th n-tile), c = b·A', and init the per-bin arena cursors.
// ---------------------------------------------------------------------------
__global__ __launch_bounds__(256) void pack_kernel(
    const float* __restrict__ W_src, const float* __restrict__ W_dst,
    const float* __restrict__ b_src, const float* __restrict__ b_dst,
    const float* __restrict__ attn,  // [8,32]
    uint4* __restrict__ wp_src, uint4* __restrict__ wp_dst,
    float* __restrict__ c_all,       // [16]
    int* __restrict__ cursor, int nCoarse)
{
    const int e = blockIdx.x * 256 + threadIdx.x;
    if (e < 4608) {
        const int which = e / 2304;
        const int e2 = e % 2304;
        const float* W = which ? W_dst : W_src;
        uint4* wp = which ? wp_dst : wp_src;
        const int aoff = which ? 16 : 0;
        short out[8];
        if (e2 < 2048) {                    // W tiles
            const int t = e2 >> 8, q = (e2 >> 6) & 3, l = e2 & 63;
            const int kbase = (l >> 4) * 8 + q * 32;
            const int n = t * 16 + (l & 15);
            #pragma unroll
            for (int j = 0; j < 8; ++j) out[j] = f2b(W[(size_t)(kbase + j) * 128 + n]);
            *(uint4*)&wp[(t * 4 + q) * 64 + l] = *(uint4*)out;
        } else {                            // V tile (fused logits)
            const int e3 = e2 - 2048;
            const int q = e3 >> 6, l = e3 & 63;
            const int kbase = (l >> 4) * 8 + q * 32;
            const int n = l & 15;
            #pragma unroll
            for (int j = 0; j < 8; ++j) {
                float v = 0.f;
                if (n < 8) {
                    for (int dd = 0; dd < 16; ++dd)
                        v += W[(size_t)(kbase + j) * 128 + n * 16 + dd] * attn[n * 32 + aoff + dd];
                }
                out[j] = f2b(v);
            }
            *(uint4*)&wp[(32 + q) * 64 + l] = *(uint4*)out;
        }
    } else if (e < 4624) {                  // c = b·A'
        const int k = e - 4608;
        const int which = k >> 3, kk = k & 7;
        const float* bb = which ? b_dst : b_src;
        const int aoff = which ? 16 : 0;
        float v = 0.f;
        for (int dd = 0; dd < 16; ++dd) v += bb[kk * 16 + dd] * attn[kk * 32 + aoff + dd];
        c_all[k] = v;
    } else if (e < 4624 + nCoarse) {        // arena cursor init
        const int c = e - 4624;
        cursor[c] = c * CAP;
    }
}

// ---------------------------------------------------------------------------
// scatter body: LDS per-bin count -> one chunk reservation per bin (returning
// atomic) -> scatter packed (s<<6 | d&63) into the bin's arena.
// ---------------------------------------------------------------------------
__device__ __forceinline__ void scatter_body(
    const int* __restrict__ src_idx, const int* __restrict__ dst_idx,
    int* __restrict__ cursor, int* __restrict__ coarse,
    int nEdges, int nCoarse, int bx)
{
    __shared__ int lcnt[MAXC];
    __shared__ int lbase[MAXC];
    const int t = threadIdx.x;
    for (int i = t; i < nCoarse; i += 256) lcnt[i] = 0;
    __syncthreads();
    const int e0 = bx * EPB;
    const int e1 = min(e0 + EPB, nEdges);
    for (int e = e0 + t; e < e1; e += 256) atomicAdd(&lcnt[dst_idx[e] >> 6], 1);
    __syncthreads();
    for (int i = t; i < nCoarse; i += 256) {
        const int c = lcnt[i];
        lbase[i] = c ? atomicAdd(&cursor[i], c) : 0;
        lcnt[i] = 0;                       // reuse as running cursor
    }
    __syncthreads();
    for (int e = e0 + t; e < e1; e += 256) {
        const int d = dst_idx[e];
        const int s = src_idx[e];
        const int bin = d >> 6;
        const int lr = atomicAdd(&lcnt[bin], 1);
        const int pos = lbase[bin] + lr;
        if (pos < (bin + 1) * CAP)         // safety clamp
            coarse[pos] = (s << 6) | (d & 63);
    }
}

// ---------------------------------------------------------------------------
// MFMA projection body: h = feat·W + b (bf16 in, fp32 acc), fused logit via
// 9th n-tile. Wave = 2 m-tiles (32 rows); block = 128 rows.
// ---------------------------------------------------------------------------
template<bool STORE_H>
__device__ __forceinline__ void proj_body(
    const float* __restrict__ feat, const uint4* __restrict__ wp,
    const float* __restrict__ b, const float* __restrict__ cvec,
    short* __restrict__ hs_out, float* __restrict__ el_out,
    int N, int bx)
{
    const int t = threadIdx.x;
    const int lane = t & 63;
    const int w = t >> 6;
    const int m  = lane & 15;
    const int q8 = lane >> 4;
    const int row0 = bx * 128 + w * 32;

    f32x4 acc0[9], acc1[9];
    #pragma unroll
    for (int tt = 0; tt < 8; ++tt) {
        const float bn = b[tt * 16 + m];
        acc0[tt] = (f32x4){bn, bn, bn, bn};
        acc1[tt] = (f32x4){bn, bn, bn, bn};
    }
    acc0[8] = (f32x4){0.f, 0.f, 0.f, 0.f};
    acc1[8] = (f32x4){0.f, 0.f, 0.f, 0.f};

    int rowA0 = row0 + m;      if (rowA0 >= N) rowA0 = N - 1;
    int rowA1 = row0 + 16 + m; if (rowA1 >= N) rowA1 = N - 1;
    const float* f0 = feat + (size_t)rowA0 * 128 + q8 * 8;
    const float* f1 = feat + (size_t)rowA1 * 128 + q8 * 8;
    const bf16x8* wpv = (const bf16x8*)wp;

    #pragma unroll
    for (int kc = 0; kc < 4; ++kc) {
        const float4 fa0 = *(const float4*)(f0 + kc * 32);
        const float4 fb0 = *(const float4*)(f0 + kc * 32 + 4);
        const float4 fa1 = *(const float4*)(f1 + kc * 32);
        const float4 fb1 = *(const float4*)(f1 + kc * 32 + 4);
        bf16x8 a0, a1;
        a0[0]=f2b(fa0.x); a0[1]=f2b(fa0.y); a0[2]=f2b(fa0.z); a0[3]=f2b(fa0.w);
        a0[4]=f2b(fb0.x); a0[5]=f2b(fb0.y); a0[6]=f2b(fb0.z); a0[7]=f2b(fb0.w);
        a1[0]=f2b(fa1.x); a1[1]=f2b(fa1.y); a1[2]=f2b(fa1.z); a1[3]=f2b(fa1.w);
        a1[4]=f2b(fb1.x); a1[5]=f2b(fb1.y); a1[6]=f2b(fb1.z); a1[7]=f2b(fb1.w);
        #pragma unroll
        for (int tt = 0; tt < 8; ++tt) {
            const bf16x8 bf = wpv[(tt * 4 + kc) * 64 + lane];
            acc0[tt] = __builtin_amdgcn_mfma_f32_16x16x32_bf16(a0, bf, acc0[tt], 0, 0, 0);
            acc1[tt] = __builtin_amdgcn_mfma_f32_16x16x32_bf16(a1, bf, acc1[tt], 0, 0, 0);
        }
        {
            const bf16x8 bv = wpv[(32 + kc) * 64 + lane];
            acc0[8] = __builtin_amdgcn_mfma_f32_16x16x32_bf16(a0, bv, acc0[8], 0, 0, 0);
            acc1[8] = __builtin_amdgcn_mfma_f32_16x16x32_bf16(a1, bv, acc1[8], 0, 0, 0);
        }
    }

    #pragma unroll
    for (int half = 0; half < 2; ++half) {
        const f32x4* acc = half ? acc1 : acc0;
        const int rbase = row0 + half * 16 + q8 * 4;
        #pragma unroll
        for (int reg = 0; reg < 4; ++reg) {
            const int row = rbase + reg;
            if (row < N) {
                if (STORE_H) {
                    #pragma unroll
                    for (int tt = 0; tt < 8; ++tt)
                        hs_out[(size_t)row * 128 + tt * 16 + m] = f2b(acc[tt][reg]);
                }
                if (m < 8) el_out[(size_t)row * 8 + m] = acc[8][reg] + cvec[m];
            }
        }
    }
}

// ---------------------------------------------------------------------------
// 1) fused: arena scatter + both MFMA projections (disjoint pipes).
// ---------------------------------------------------------------------------
__global__ __launch_bounds__(256, 2) void fused_kernel(
    const float* __restrict__ feat_src, const float* __restrict__ feat_dst,
    const uint4* __restrict__ wp_src, const uint4* __restrict__ wp_dst,
    const float* __restrict__ b_src, const float* __restrict__ b_dst,
    const float* __restrict__ c_all,
    short* __restrict__ hs, float* __restrict__ el, float* __restrict__ er,
    const int* __restrict__ src_idx, const int* __restrict__ dst_idx,
    int* __restrict__ cursor, int* __restrict__ coarse,
    int n_src, int n_dst, int nEdges, int nCoarse, int nSB, int pSrcBlocks)
{
    int bx = blockIdx.x;
    if (bx < nSB) { scatter_body(src_idx, dst_idx, cursor, coarse, nEdges, nCoarse, bx); return; }
    bx -= nSB;
    if (bx < pSrcBlocks) {
        proj_body<true>(feat_src, wp_src, b_src, c_all, hs, el, n_src, bx);
        return;
    }
    bx -= pSrcBlocks;
    proj_body<false>(feat_dst, wp_dst, b_dst, c_all + 8, nullptr, er, n_dst, bx);
}

// ---------------------------------------------------------------------------
// 2) sort+reduce: one block per 64-dst bin. LDS counting sort of the bin's
//    arena slice, then the SAME block reduces all 64 dsts straight from LDS:
//    no pw / sorted_src / off arrays, no extra dispatches. Weights
//    ee = exp(leakyrelu(el[s]+er[d])) recomputed in fp32 in the loop.
//    Wave w handles dsts w*16..w*16+15; half-wave per edge (lane: 4 channels).
// ---------------------------------------------------------------------------
__global__ __launch_bounds__(256) void sort_reduce_kernel(
    const int* __restrict__ coarse, const int* __restrict__ cursor,
    const float* __restrict__ el,   // [N_src,8]
    const float* __restrict__ er,   // [N_dst,8]
    const unsigned short* __restrict__ hs, // [N_src,128] bf16 bits
    float* __restrict__ out,        // [N_dst,128]
    int n_dst, int nCoarse)
{
    __shared__ int fpk[CAP];        // 16 KB sorted packed edges
    __shared__ int h[64];           // per-dst degree
    __shared__ int lbeg[64];        // per-dst local start
    __shared__ int cu[64];
    __shared__ float erL[64 * 8];
    const int t = threadIdx.x, c = blockIdx.x;
    const int base_in = c * CAP;
    const int cnt = min(cursor[c] - base_in, CAP);

    for (int i = t; i < 512; i += 256) {    // er preload: contiguous c*512 + i
        const int d = c * 64 + (i >> 3);
        erL[i] = (d < n_dst) ? er[(size_t)d * 8 + (i & 7)] : 0.f;
    }
    if (t < 64) h[t] = 0;
    __syncthreads();
    for (int i = t; i < cnt; i += 256) atomicAdd(&h[coarse[base_in + i] & 63], 1);
    __syncthreads();
    if (t == 0) {
        int run = 0;
        #pragma unroll
        for (int j = 0; j < 64; ++j) { cu[j] = run; lbeg[j] = run; run += h[j]; }
    }
    __syncthreads();
    for (int i = t; i < cnt; i += 256) {
        const int v = coarse[base_in + i];
        const int p = atomicAdd(&cu[v & 63], 1);
        fpk[p] = v;
    }
    __syncthreads();

    const int w = t >> 6, lane = t & 63;
    const int sub = lane >> 5;        // which edge of the pair
    const int l32 = lane & 31;        // channel group 4*l32..4*l32+3
    const int k   = l32 >> 2;         // head
    for (int j = 0; j < 16; ++j) {
        const int dl = w * 16 + j;
        const int d  = c * 64 + dl;
        if (d >= n_dst) break;        // wave-uniform
        const float erk = erL[dl * 8 + k];
        const int beg = lbeg[dl], end = lbeg[dl] + h[dl];
        float a0 = 0.f, a1 = 0.f, a2 = 0.f, a3 = 0.f, es = 0.f;
        int i = beg + sub;
        for (; i + 2 < end; i += 4) {
            const int sA = fpk[i] >> 6;
            const int sB = fpk[i + 2] >> 6;
            const float lA = el[(size_t)sA * 8 + k];
            const float lB = el[(size_t)sB * 8 + k];
            const uint2 uA = ((const uint2*)(hs + (size_t)sA * 128))[l32];
            const uint2 uB = ((const uint2*)(hs + (size_t)sB * 128))[l32];
            float xA = lA + erk; xA = (xA >= 0.f) ? xA : NEG_SLOPE * xA;
            float xB = lB + erk; xB = (xB >= 0.f) ? xB : NEG_SLOPE * xB;
            const float eA = __expf(xA);
            const float eB = __expf(xB);
            es += eA + eB;
            a0 = fmaf(eA, b2f_lo(uA.x), a0); a1 = fmaf(eA, b2f_hi(uA.x), a1);
            a2 = fmaf(eA, b2f_lo(uA.y), a2); a3 = fmaf(eA, b2f_hi(uA.y), a3);
            a0 = fmaf(eB, b2f_lo(uB.x), a0); a1 = fmaf(eB, b2f_hi(uB.x), a1);
            a2 = fmaf(eB, b2f_lo(uB.y), a2); a3 = fmaf(eB, b2f_hi(uB.y), a3);
        }
        for (; i < end; i += 2) {
            const int s = fpk[i] >> 6;
            const float l = el[(size_t)s * 8 + k];
            const uint2 u = ((const uint2*)(hs + (size_t)s * 128))[l32];
            float x = l + erk; x = (x >= 0.f) ? x : NEG_SLOPE * x;
            const float ee = __expf(x);
            es += ee;
            a0 = fmaf(ee, b2f_lo(u.x), a0); a1 = fmaf(ee, b2f_hi(u.x), a1);
            a2 = fmaf(ee, b2f_lo(u.y), a2); a3 = fmaf(ee, b2f_hi(u.y), a3);
        }
        es += __shfl_xor(es, 32);
        a0 += __shfl_xor(a0, 32);
        a1 += __shfl_xor(a1, 32);
        a2 += __shfl_xor(a2, 32);
        a3 += __shfl_xor(a3, 32);
        if (sub == 0) {
            const float inv = (es > 0.f) ? 1.f / es : 0.f;
            float4 o;
            o.x = a0 * inv; o.y = a1 * inv; o.z = a2 * inv; o.w = a3 * inv;
            *(float4*)(out + (size_t)d * 128 + l32 * 4) = o;
        }
    }
}

extern "C" void kernel_launch(void* const* d_in, const int* in_sizes, int n_in,
                              void* d_out, int out_size, void* d_ws, size_t ws_size,
                              hipStream_t stream) {
    const float* feat_src = (const float*)d_in[0];
    const float* feat_dst = (const float*)d_in[1];
    const float* W_src    = (const float*)d_in[2];
    const float* b_src    = (const float*)d_in[3];
    const float* W_dst    = (const float*)d_in[4];
    const float* b_dst    = (const float*)d_in[5];
    const float* attn     = (const float*)d_in[6];
    const int*   src_idx  = (const int*)d_in[7];
    const int*   dst_idx  = (const int*)d_in[8];
    float* out = (float*)d_out;

    const int n_src  = in_sizes[0] / 128;
    const int n_dst  = in_sizes[1] / 128;
    const int nEdges = in_sizes[7];

    const int nCoarse = (n_dst + 63) >> 6;                 // 782
    const int nSB     = (nEdges + EPB - 1) / EPB;          // 196
    const int pSrc    = (n_src + 127) / 128;
    const int pDst    = (n_dst + 127) / 128;

    // workspace layout
    unsigned short* hs = (unsigned short*)d_ws;            // n_src*128 bf16 (12.8 MB)
    float* el = (float*)(hs + (size_t)n_src * 128);        // n_src*8
    float* er = el + (size_t)n_src * 8;                    // n_dst*8
    int* cursor = (int*)(er + (size_t)n_dst * 8);          // nCoarse
    uintptr_t p = (uintptr_t)(cursor + nCoarse);
    p = (p + 15) & ~(uintptr_t)15;
    int* coarse = (int*)p;                                 // nCoarse*CAP (12.8 MB)
    uintptr_t p2 = (uintptr_t)(coarse + (size_t)nCoarse * CAP);
    p2 = (p2 + 15) & ~(uintptr_t)15;
    uint4* wp_src = (uint4*)p2;                            // 36*64 uint4
    uint4* wp_dst = wp_src + 36 * 64;                      // 36*64 uint4
    float* c_all  = (float*)(wp_dst + 36 * 64);            // 16 floats

    pack_kernel<<<22, 256, 0, stream>>>(W_src, W_dst, b_src, b_dst, attn,
                                        wp_src, wp_dst, c_all, cursor, nCoarse);

    fused_kernel<<<nSB + pSrc + pDst, 256, 0, stream>>>(
        feat_src, feat_dst, wp_src, wp_dst, b_src, b_dst, c_all,
        (short*)hs, el, er, src_idx, dst_idx, cursor, coarse,
        n_src, n_dst, nEdges, nCoarse, nSB, pSrc);

    sort_reduce_kernel<<<nCoarse, 256, 0, stream>>>(coarse, cursor, el, er,
                                                    hs, out, n_dst, nCoarse);
}

// Round 12
// 232.443 us; speedup vs baseline: 1.1169x; 1.0254x over previous
//
#include <hip/hip_runtime.h>
#include <hip/hip_bf16.h>

#define NEG_SLOPE 0.2f
#define EPB   8192   // edges per scatter block
#define CAP   4096   // arena slots per 64-dst coarse bin (mean 2048, sigma 45)
#define MAXC  1024   // max coarse bins; ceil(50000/64) = 782

typedef __attribute__((ext_vector_type(8))) short bf16x8;
typedef __attribute__((ext_vector_type(4))) float f32x4;

__device__ __forceinline__ float b2f_lo(unsigned u) { return __uint_as_float(u << 16); }
__device__ __forceinline__ float b2f_hi(unsigned u) { return __uint_as_float(u & 0xffff0000u); }

__device__ __forceinline__ short f2b(float x) {
    unsigned u = __float_as_uint(x);
    unsigned r = (u + 0x7fffu + ((u >> 16) & 1u)) >> 16;
    return (short)r;
}

// ---------------------------------------------------------------------------
// 0) Pack W into MFMA B-fragment order (bf16) + fused logit matrix V = W·A'
//    (9th n-tile), c = b·A', and init the per-bin arena cursors.
// ---------------------------------------------------------------------------
__global__ __launch_bounds__(256) void pack_kernel(
    const float* __restrict__ W_src, const float* __restrict__ W_dst,
    const float* __restrict__ b_src, const float* __restrict__ b_dst,
    const float* __restrict__ attn,  // [8,32]
    uint4* __restrict__ wp_src, uint4* __restrict__ wp_dst,
    float* __restrict__ c_all,       // [16]
    int* __restrict__ cursor, int nCoarse)
{
    const int e = blockIdx.x * 256 + threadIdx.x;
    if (e < 4608) {
        const int which = e / 2304;
        const int e2 = e % 2304;
        const float* W = which ? W_dst : W_src;
        uint4* wp = which ? wp_dst : wp_src;
        const int aoff = which ? 16 : 0;
        short out[8];
        if (e2 < 2048) {                    // W tiles
            const int t = e2 >> 8, q = (e2 >> 6) & 3, l = e2 & 63;
            const int kbase = (l >> 4) * 8 + q * 32;
            const int n = t * 16 + (l & 15);
            #pragma unroll
            for (int j = 0; j < 8; ++j) out[j] = f2b(W[(size_t)(kbase + j) * 128 + n]);
            *(uint4*)&wp[(t * 4 + q) * 64 + l] = *(uint4*)out;
        } else {                            // V tile (fused logits)
            const int e3 = e2 - 2048;
            const int q = e3 >> 6, l = e3 & 63;
            const int kbase = (l >> 4) * 8 + q * 32;
            const int n = l & 15;
            #pragma unroll
            for (int j = 0; j < 8; ++j) {
                float v = 0.f;
                if (n < 8) {
                    for (int dd = 0; dd < 16; ++dd)
                        v += W[(size_t)(kbase + j) * 128 + n * 16 + dd] * attn[n * 32 + aoff + dd];
                }
                out[j] = f2b(v);
            }
            *(uint4*)&wp[(32 + q) * 64 + l] = *(uint4*)out;
        }
    } else if (e < 4624) {                  // c = b·A'
        const int k = e - 4608;
        const int which = k >> 3, kk = k & 7;
        const float* bb = which ? b_dst : b_src;
        const int aoff = which ? 16 : 0;
        float v = 0.f;
        for (int dd = 0; dd < 16; ++dd) v += bb[kk * 16 + dd] * attn[kk * 32 + aoff + dd];
        c_all[k] = v;
    } else if (e < 4624 + nCoarse) {        // arena cursor init
        const int c = e - 4624;
        cursor[c] = c * CAP;
    }
}

// ---------------------------------------------------------------------------
// scatter body: LDS per-bin count -> one chunk reservation per bin (returning
// atomic) -> scatter packed (s<<6 | d&63) into the bin's arena.
// ---------------------------------------------------------------------------
__device__ __forceinline__ void scatter_body(
    const int* __restrict__ src_idx, const int* __restrict__ dst_idx,
    int* __restrict__ cursor, int* __restrict__ coarse,
    int nEdges, int nCoarse, int bx)
{
    __shared__ int lcnt[MAXC];
    __shared__ int lbase[MAXC];
    const int t = threadIdx.x;
    for (int i = t; i < nCoarse; i += 256) lcnt[i] = 0;
    __syncthreads();
    const int e0 = bx * EPB;
    const int e1 = min(e0 + EPB, nEdges);
    for (int e = e0 + t; e < e1; e += 256) atomicAdd(&lcnt[dst_idx[e] >> 6], 1);
    __syncthreads();
    for (int i = t; i < nCoarse; i += 256) {
        const int c = lcnt[i];
        lbase[i] = c ? atomicAdd(&cursor[i], c) : 0;
        lcnt[i] = 0;                       // reuse as running cursor
    }
    __syncthreads();
    for (int e = e0 + t; e < e1; e += 256) {
        const int d = dst_idx[e];
        const int s = src_idx[e];
        const int bin = d >> 6;
        const int lr = atomicAdd(&lcnt[bin], 1);
        const int pos = lbase[bin] + lr;
        if (pos < (bin + 1) * CAP)         // safety clamp
            coarse[pos] = (s << 6) | (d & 63);
    }
}

// ---------------------------------------------------------------------------
// MFMA projection body: h = feat·W + b (bf16 in, fp32 acc), fused logit via
// 9th n-tile. Wave = 2 m-tiles (32 rows); block = 128 rows.
// ---------------------------------------------------------------------------
template<bool STORE_H>
__device__ __forceinline__ void proj_body(
    const float* __restrict__ feat, const uint4* __restrict__ wp,
    const float* __restrict__ b, const float* __restrict__ cvec,
    short* __restrict__ hs_out, float* __restrict__ el_out,
    int N, int bx)
{
    const int t = threadIdx.x;
    const int lane = t & 63;
    const int w = t >> 6;
    const int m  = lane & 15;
    const int q8 = lane >> 4;
    const int row0 = bx * 128 + w * 32;

    f32x4 acc0[9], acc1[9];
    #pragma unroll
    for (int tt = 0; tt < 8; ++tt) {
        const float bn = b[tt * 16 + m];
        acc0[tt] = (f32x4){bn, bn, bn, bn};
        acc1[tt] = (f32x4){bn, bn, bn, bn};
    }
    acc0[8] = (f32x4){0.f, 0.f, 0.f, 0.f};
    acc1[8] = (f32x4){0.f, 0.f, 0.f, 0.f};

    int rowA0 = row0 + m;      if (rowA0 >= N) rowA0 = N - 1;
    int rowA1 = row0 + 16 + m; if (rowA1 >= N) rowA1 = N - 1;
    const float* f0 = feat + (size_t)rowA0 * 128 + q8 * 8;
    const float* f1 = feat + (size_t)rowA1 * 128 + q8 * 8;
    const bf16x8* wpv = (const bf16x8*)wp;

    #pragma unroll
    for (int kc = 0; kc < 4; ++kc) {
        const float4 fa0 = *(const float4*)(f0 + kc * 32);
        const float4 fb0 = *(const float4*)(f0 + kc * 32 + 4);
        const float4 fa1 = *(const float4*)(f1 + kc * 32);
        const float4 fb1 = *(const float4*)(f1 + kc * 32 + 4);
        bf16x8 a0, a1;
        a0[0]=f2b(fa0.x); a0[1]=f2b(fa0.y); a0[2]=f2b(fa0.z); a0[3]=f2b(fa0.w);
        a0[4]=f2b(fb0.x); a0[5]=f2b(fb0.y); a0[6]=f2b(fb0.z); a0[7]=f2b(fb0.w);
        a1[0]=f2b(fa1.x); a1[1]=f2b(fa1.y); a1[2]=f2b(fa1.z); a1[3]=f2b(fa1.w);
        a1[4]=f2b(fb1.x); a1[5]=f2b(fb1.y); a1[6]=f2b(fb1.z); a1[7]=f2b(fb1.w);
        #pragma unroll
        for (int tt = 0; tt < 8; ++tt) {
            const bf16x8 bf = wpv[(tt * 4 + kc) * 64 + lane];
            acc0[tt] = __builtin_amdgcn_mfma_f32_16x16x32_bf16(a0, bf, acc0[tt], 0, 0, 0);
            acc1[tt] = __builtin_amdgcn_mfma_f32_16x16x32_bf16(a1, bf, acc1[tt], 0, 0, 0);
        }
        {
            const bf16x8 bv = wpv[(32 + kc) * 64 + lane];
            acc0[8] = __builtin_amdgcn_mfma_f32_16x16x32_bf16(a0, bv, acc0[8], 0, 0, 0);
            acc1[8] = __builtin_amdgcn_mfma_f32_16x16x32_bf16(a1, bv, acc1[8], 0, 0, 0);
        }
    }

    #pragma unroll
    for (int half = 0; half < 2; ++half) {
        const f32x4* acc = half ? acc1 : acc0;
        const int rbase = row0 + half * 16 + q8 * 4;
        #pragma unroll
        for (int reg = 0; reg < 4; ++reg) {
            const int row = rbase + reg;
            if (row < N) {
                if (STORE_H) {
                    #pragma unroll
                    for (int tt = 0; tt < 8; ++tt)
                        hs_out[(size_t)row * 128 + tt * 16 + m] = f2b(acc[tt][reg]);
                }
                if (m < 8) el_out[(size_t)row * 8 + m] = acc[8][reg] + cvec[m];
            }
        }
    }
}

// ---------------------------------------------------------------------------
// 1) fused: arena scatter + both MFMA projections (disjoint pipes).
// ---------------------------------------------------------------------------
__global__ __launch_bounds__(256, 2) void fused_kernel(
    const float* __restrict__ feat_src, const float* __restrict__ feat_dst,
    const uint4* __restrict__ wp_src, const uint4* __restrict__ wp_dst,
    const float* __restrict__ b_src, const float* __restrict__ b_dst,
    const float* __restrict__ c_all,
    short* __restrict__ hs, float* __restrict__ el, float* __restrict__ er,
    const int* __restrict__ src_idx, const int* __restrict__ dst_idx,
    int* __restrict__ cursor, int* __restrict__ coarse,
    int n_src, int n_dst, int nEdges, int nCoarse, int nSB, int pSrcBlocks)
{
    int bx = blockIdx.x;
    if (bx < nSB) { scatter_body(src_idx, dst_idx, cursor, coarse, nEdges, nCoarse, bx); return; }
    bx -= nSB;
    if (bx < pSrcBlocks) {
        proj_body<true>(feat_src, wp_src, b_src, c_all, hs, el, n_src, bx);
        return;
    }
    bx -= pSrcBlocks;
    proj_body<false>(feat_dst, wp_dst, b_dst, c_all + 8, nullptr, er, n_dst, bx);
}

// ---------------------------------------------------------------------------
// 2) sort+reduce: one 512-thread block (8 waves) per 64-dst bin. LDS counting
//    sort of the bin's arena slice, then the same block reduces all 64 dsts
//    straight from LDS (wave w: dsts w*8..w*8+7; half-wave per edge).
//    512 threads/block -> ~24 waves/CU at 782 blocks (vs 12 at 256) for
//    gather-latency hiding.
// ---------------------------------------------------------------------------
__global__ __launch_bounds__(512) void sort_reduce_kernel(
    const int* __restrict__ coarse, const int* __restrict__ cursor,
    const float* __restrict__ el,   // [N_src,8]
    const float* __restrict__ er,   // [N_dst,8]
    const unsigned short* __restrict__ hs, // [N_src,128] bf16 bits
    float* __restrict__ out,        // [N_dst,128]
    int n_dst, int nCoarse)
{
    __shared__ int fpk[CAP];        // 16 KB sorted packed edges
    __shared__ int h[64];           // per-dst degree
    __shared__ int lbeg[64];        // per-dst local start
    __shared__ int cu[64];
    __shared__ float erL[64 * 8];
    const int t = threadIdx.x, c = blockIdx.x;
    const int base_in = c * CAP;
    const int cnt = min(cursor[c] - base_in, CAP);

    if (t < 512) {                          // er preload
        const int d = c * 64 + (t >> 3);
        erL[t] = (d < n_dst) ? er[(size_t)d * 8 + (t & 7)] : 0.f;
    }
    if (t < 64) h[t] = 0;
    __syncthreads();
    for (int i = t; i < cnt; i += 512) atomicAdd(&h[coarse[base_in + i] & 63], 1);
    __syncthreads();
    if (t == 0) {
        int run = 0;
        #pragma unroll
        for (int j = 0; j < 64; ++j) { cu[j] = run; lbeg[j] = run; run += h[j]; }
    }
    __syncthreads();
    for (int i = t; i < cnt; i += 512) {
        const int v = coarse[base_in + i];
        const int p = atomicAdd(&cu[v & 63], 1);
        fpk[p] = v;
    }
    __syncthreads();

    const int w = t >> 6, lane = t & 63;    // w in 0..7
    const int sub = lane >> 5;        // which edge of the pair
    const int l32 = lane & 31;        // channel group 4*l32..4*l32+3
    const int k   = l32 >> 2;         // head
    for (int j = 0; j < 8; ++j) {
        const int dl = w * 8 + j;
        const int d  = c * 64 + dl;
        if (d >= n_dst) break;        // wave-uniform
        const float erk = erL[dl * 8 + k];
        const int beg = lbeg[dl], end = lbeg[dl] + h[dl];
        float a0 = 0.f, a1 = 0.f, a2 = 0.f, a3 = 0.f, es = 0.f;
        int i = beg + sub;
        for (; i + 2 < end; i += 4) {
            const int sA = fpk[i] >> 6;
            const int sB = fpk[i + 2] >> 6;
            const float lA = el[(size_t)sA * 8 + k];
            const float lB = el[(size_t)sB * 8 + k];
            const uint2 uA = ((const uint2*)(hs + (size_t)sA * 128))[l32];
            const uint2 uB = ((const uint2*)(hs + (size_t)sB * 128))[l32];
            float xA = lA + erk; xA = (xA >= 0.f) ? xA : NEG_SLOPE * xA;
            float xB = lB + erk; xB = (xB >= 0.f) ? xB : NEG_SLOPE * xB;
            const float eA = __expf(xA);
            const float eB = __expf(xB);
            es += eA + eB;
            a0 = fmaf(eA, b2f_lo(uA.x), a0); a1 = fmaf(eA, b2f_hi(uA.x), a1);
            a2 = fmaf(eA, b2f_lo(uA.y), a2); a3 = fmaf(eA, b2f_hi(uA.y), a3);
            a0 = fmaf(eB, b2f_lo(uB.x), a0); a1 = fmaf(eB, b2f_hi(uB.x), a1);
            a2 = fmaf(eB, b2f_lo(uB.y), a2); a3 = fmaf(eB, b2f_hi(uB.y), a3);
        }
        for (; i < end; i += 2) {
            const int s = fpk[i] >> 6;
            const float l = el[(size_t)s * 8 + k];
            const uint2 u = ((const uint2*)(hs + (size_t)s * 128))[l32];
            float x = l + erk; x = (x >= 0.f) ? x : NEG_SLOPE * x;
            const float ee = __expf(x);
            es += ee;
            a0 = fmaf(ee, b2f_lo(u.x), a0); a1 = fmaf(ee, b2f_hi(u.x), a1);
            a2 = fmaf(ee, b2f_lo(u.y), a2); a3 = fmaf(ee, b2f_hi(u.y), a3);
        }
        es += __shfl_xor(es, 32);
        a0 += __shfl_xor(a0, 32);
        a1 += __shfl_xor(a1, 32);
        a2 += __shfl_xor(a2, 32);
        a3 += __shfl_xor(a3, 32);
        if (sub == 0) {
            const float inv = (es > 0.f) ? 1.f / es : 0.f;
            float4 o;
            o.x = a0 * inv; o.y = a1 * inv; o.z = a2 * inv; o.w = a3 * inv;
            *(float4*)(out + (size_t)d * 128 + l32 * 4) = o;
        }
    }
}

extern "C" void kernel_launch(void* const* d_in, const int* in_sizes, int n_in,
                              void* d_out, int out_size, void* d_ws, size_t ws_size,
                              hipStream_t stream) {
    const float* feat_src = (const float*)d_in[0];
    const float* feat_dst = (const float*)d_in[1];
    const float* W_src    = (const float*)d_in[2];
    const float* b_src    = (const float*)d_in[3];
    const float* W_dst    = (const float*)d_in[4];
    const float* b_dst    = (const float*)d_in[5];
    const float* attn     = (const float*)d_in[6];
    const int*   src_idx  = (const int*)d_in[7];
    const int*   dst_idx  = (const int*)d_in[8];
    float* out = (float*)d_out;

    const int n_src  = in_sizes[0] / 128;
    const int n_dst  = in_sizes[1] / 128;
    const int nEdges = in_sizes[7];

    const int nCoarse = (n_dst + 63) >> 6;                 // 782
    const int nSB     = (nEdges + EPB - 1) / EPB;          // 196
    const int pSrc    = (n_src + 127) / 128;
    const int pDst    = (n_dst + 127) / 128;

    // workspace layout
    unsigned short* hs = (unsigned short*)d_ws;            // n_src*128 bf16 (12.8 MB)
    float* el = (float*)(hs + (size_t)n_src * 128);        // n_src*8
    float* er = el + (size_t)n_src * 8;                    // n_dst*8
    int* cursor = (int*)(er + (size_t)n_dst * 8);          // nCoarse
    uintptr_t p = (uintptr_t)(cursor + nCoarse);
    p = (p + 15) & ~(uintptr_t)15;
    int* coarse = (int*)p;                                 // nCoarse*CAP (12.8 MB)
    uintptr_t p2 = (uintptr_t)(coarse + (size_t)nCoarse * CAP);
    p2 = (p2 + 15) & ~(uintptr_t)15;
    uint4* wp_src = (uint4*)p2;                            // 36*64 uint4
    uint4* wp_dst = wp_src + 36 * 64;                      // 36*64 uint4
    float* c_all  = (float*)(wp_dst + 36 * 64);            // 16 floats

    pack_kernel<<<22, 256, 0, stream>>>(W_src, W_dst, b_src, b_dst, attn,
                                        wp_src, wp_dst, c_all, cursor, nCoarse);

    fused_kernel<<<nSB + pSrc + pDst, 256, 0, stream>>>(
        feat_src, feat_dst, wp_src, wp_dst, b_src, b_dst, c_all,
        (short*)hs, el, er, src_idx, dst_idx, cursor, coarse,
        n_src, n_dst, nEdges, nCoarse, nSB, pSrc);

    sort_reduce_kernel<<<nCoarse, 512, 0, stream>>>(coarse, cursor, el, er,
                                                    hs, out, n_dst, nCoarse);
}